// Round 5
// baseline (328.263 us; speedup 1.0000x reference)
//
#include <hip/hip_runtime.h>
#include <stdint.h>

#define BATCH 16
#define NBOX  32768
#define PRE   4096
#define POST  512

// LDS pad for u64 bitonic arrays: slot(i) = i + (i>>4) breaks the 8-way
// bank conflict at jj in {1,2,4} (lane-stride 16-element collisions).
#define PADIDX(i) ((i) + ((i) >> 4))

typedef unsigned long long u64;
typedef unsigned int u32;

__device__ inline u64 shfl64(u64 v, int src) {
    int lo = __shfl((int)(v & 0xffffffffULL), src);
    int hi = __shfl((int)(v >> 32), src);
    return ((u64)(u32)hi << 32) | (u32)lo;
}

// ---------------------------------------------------------------------------
// K1: fused keygen + LDS bitonic sort of a 4096-key chunk (ascending).
// key = (~score_bits)<<32 | box_index  -> ascending == lax.top_k order.
// Padded LDS kills the jj<=4 bank conflicts.
// ---------------------------------------------------------------------------
__global__ __launch_bounds__(1024) void k_sortkeys4096(const float* __restrict__ cls,
                                                       u64* __restrict__ out) {
    __shared__ u64 s[PRE + (PRE >> 4)];   // 4352 * 8 = 34.8 KB
    int g = blockIdx.x;                   // global chunk: g = b*8 + c
    u64* dst = out + (size_t)g * PRE;
    int tid = threadIdx.x;
    for (int i = tid; i < PRE; i += 1024) {
        int idx = g * PRE + i;            // global box index (b*NBOX + n)
        const float* c = cls + (size_t)idx * 3;
        float sc = fmaxf(fmaxf(c[0], c[1]), c[2]);
        u32 sb = __float_as_uint(sc);     // scores >= 0 -> monotonic bits
        s[PADIDX(i)] = ((u64)(~sb) << 32) | (u32)(idx & (NBOX - 1));
    }
    for (int k = 2; k <= PRE; k <<= 1) {
        for (int jj = k >> 1; jj > 0; jj >>= 1) {
            __syncthreads();
            for (int p = tid; p < PRE / 2; p += 1024) {
                int i = 2 * p - (p & (jj - 1));
                int l = i + jj;
                bool asc = ((i & k) == 0);
                u64 a = s[PADIDX(i)], b = s[PADIDX(l)];
                if ((a > b) == asc) { s[PADIDX(i)] = b; s[PADIDX(l)] = a; }
            }
        }
    }
    __syncthreads();
    for (int i = tid; i < PRE; i += 1024) dst[i] = s[PADIDX(i)];
}

// ---------------------------------------------------------------------------
// K2: merge-path merge of two ascending 4096-lists, keep smallest 4096.
// Each thread binary-searches its diagonal, then merges 16 elements
// sequentially in registers. One barrier total (after LDS stage-in).
// Sentinel ~0ULL > any real key (index < 2^15 in low bits).
// ---------------------------------------------------------------------------
__global__ __launch_bounds__(256) void k_mergepath(const u64* __restrict__ in,
                                                   u64* __restrict__ out, int npairs) {
    __shared__ u64 sA[PRE], sB[PRE];
    int b = blockIdx.x / npairs, p = blockIdx.x % npairs;
    const u64* A  = in + ((size_t)b * npairs * 2 + (size_t)p * 2) * PRE;
    const u64* Bp = A + PRE;
    u64* dst = out + ((size_t)b * npairs + p) * PRE;
    int tid = threadIdx.x;
    for (int i = tid; i < PRE; i += 256) { sA[i] = A[i]; sB[i] = Bp[i]; }
    __syncthreads();
    int d = tid * 16;
    int lo = d > PRE ? d - PRE : 0;
    int hi = d < PRE ? d : PRE;
    while (lo < hi) {
        int mid = (lo + hi) >> 1;
        if (sA[mid] < sB[d - 1 - mid]) lo = mid + 1; else hi = mid;
    }
    int a = lo, bi = d - lo;
    u64 av = a  < PRE ? sA[a]  : ~0ULL;
    u64 bv = bi < PRE ? sB[bi] : ~0ULL;
    u64 res[16];
    #pragma unroll
    for (int q = 0; q < 16; ++q) {
        bool ta = av < bv;
        res[q] = ta ? av : bv;
        if (ta) { ++a;  av = a  < PRE ? sA[a]  : ~0ULL; }
        else    { ++bi; bv = bi < PRE ? sB[bi] : ~0ULL; }
    }
    #pragma unroll
    for (int q = 0; q < 16; ++q) dst[d + q] = res[q];
}

// ---------------------------------------------------------------------------
// K3: per-candidate coord extraction (1 thread = 1 candidate, 64K threads)
// + zero the flag words. Exact-FP corner math (rn ops, no fma contraction).
// ---------------------------------------------------------------------------
__global__ __launch_bounds__(256) void k_coords(const u64* __restrict__ topkeys,
                                                const float* __restrict__ boxes,
                                                float* __restrict__ cx1,
                                                float* __restrict__ cy1,
                                                float* __restrict__ cx2,
                                                float* __restrict__ cy2,
                                                float* __restrict__ car,
                                                u64* __restrict__ flags) {
    int g = blockIdx.x * 256 + threadIdx.x;   // 0 .. B*PRE-1
    if (g < BATCH * 64) flags[g] = 0ULL;
    int b = g >> 12;                          // PRE = 4096
    u64 key = topkeys[g];
    int n = (int)(key & 0xffffffffULL);
    const float* bp = boxes + ((size_t)b * NBOX + n) * 7;
    float cx = bp[0], cy = bp[1], dx = bp[3], dy = bp[4];
    float hx = __fmul_rn(dx, 0.5f), hy = __fmul_rn(dy, 0.5f);
    float x1 = __fsub_rn(cx, hx), x2 = __fadd_rn(cx, hx);
    float y1 = __fsub_rn(cy, hy), y2 = __fadd_rn(cy, hy);
    cx1[g] = x1; cy1[g] = y1; cx2[g] = x2; cy2[g] = y2;
    car[g] = __fmul_rn(__fsub_rn(x2, x1), __fsub_rn(y2, y1));
}

// ---------------------------------------------------------------------------
// K4: pairwise suppression matrix, uniform tiles. Tile = (64-row block, word).
// blockIdx.x in [0,2080) decodes to (blk, wd) with wd >= blk (triangle).
// Division-free exact threshold: RN32(p/q) >= 0.7f  <=>  p > (0.7f-2^-25)*q,
// evaluated in f64 (25-bit * 24-bit product is exact in f64).
// Off-diagonal tiles have j > i unconditionally.
// ---------------------------------------------------------------------------
__global__ __launch_bounds__(256) void k_iou(const float* __restrict__ cx1,
                                             const float* __restrict__ cy1,
                                             const float* __restrict__ cx2,
                                             const float* __restrict__ cy2,
                                             const float* __restrict__ car,
                                             u64* __restrict__ maskp,
                                             u64* __restrict__ flags) {
    __shared__ float s1[64], s2[64], s3[64], s4[64], s5[64];
    int b = blockIdx.y;
    int t = blockIdx.x, blk = 0;
    while (t >= 64 - blk) { t -= 64 - blk; ++blk; }
    int wd = blk + t;
    bool diag = (wd == blk);
    size_t base = (size_t)b * PRE;
    int tid = threadIdx.x;
    if (tid < 64) {
        int i = blk * 64 + tid;
        s1[tid] = cx1[base + i]; s2[tid] = cy1[base + i];
        s3[tid] = cx2[base + i]; s4[tid] = cy2[base + i];
        s5[tid] = car[base + i];
    }
    __syncthreads();
    int w = tid >> 6, lane = tid & 63;
    int j = wd * 64 + lane;
    float jx1 = cx1[base + j], jy1 = cy1[base + j];
    float jx2 = cx2[base + j], jy2 = cy2[base + j];
    float ja  = car[base + j];
    const double M = (double)0.7f - 0x1p-25;   // exact rounding boundary
    u64 wavebits = 0;
    int r0 = w * 16;
    #pragma unroll 4
    for (int r = 0; r < 16; ++r) {
        int i = blk * 64 + r0 + r;
        float rx1 = s1[r0 + r], ry1 = s2[r0 + r];
        float rx2 = s3[r0 + r], ry2 = s4[r0 + r], ra = s5[r0 + r];
        float ix = fmaxf(__fsub_rn(fminf(jx2, rx2), fmaxf(jx1, rx1)), 0.0f);
        float iy = fmaxf(__fsub_rn(fminf(jy2, ry2), fmaxf(jy1, ry1)), 0.0f);
        float inter = __fmul_rn(ix, iy);
        bool cand = (inter > 0.0f) && (!diag || j > i);
        u64 m = 0;
        if (__ballot(cand)) {
            float ssum = __fadd_rn(ja, ra);
            float d    = __fsub_rn(ssum, inter);
            float q    = __fadd_rn(d, 1e-8f);
            bool sup = cand && ((double)inter > M * (double)q);
            m = __ballot(sup);
        }
        if (lane == 0) maskp[((base + i) << 6) + wd] = m;
        if (m) wavebits |= 1ULL << (r0 + r);
    }
    if (lane == 0 && wavebits)
        atomicOr((unsigned long long*)&flags[b * 64 + blk], wavebits);
}

// ---------------------------------------------------------------------------
// K5: register-resident greedy walk (1 wave/batch) + output gather.
// ---------------------------------------------------------------------------
__global__ __launch_bounds__(256) void k_walk(const u64* __restrict__ maskp,
                                              const u64* __restrict__ flagbits,
                                              const u64* __restrict__ topkeys,
                                              const float* __restrict__ boxes,
                                              const float* __restrict__ cls,
                                              float* __restrict__ out) {
    __shared__ int ssel[POST];
    __shared__ int scnt;
    int b = blockIdx.x;
    int tid = threadIdx.x;
    const u64* keys = topkeys + (size_t)b * PRE;

    if (tid < 64) {
        int lane = tid;
        u64 act = ~0ULL;
        u64 nzf = flagbits[b * 64 + lane];
        int cnt = 0;
        while (true) {
            u64 bal = __ballot(act != 0ULL);
            if (!bal) break;
            int fw = __ffsll(bal) - 1;
            u64 wsel = shfl64(act, fw);
            int i = (fw << 6) + __ffsll(wsel) - 1;
            if (lane == 0) ssel[cnt] = i;
            cnt++;
            if (cnt == POST) break;
            if (lane == fw) act &= ~(1ULL << (i & 63));
            u64 fword = shfl64(nzf, fw);
            if ((fword >> (i & 63)) & 1ULL) {
                u64 row = maskp[(((size_t)b * PRE + i) << 6) + lane];
                if (lane >= fw) act &= ~row;   // words < fw were never written
            }
        }
        if (lane == 0) scnt = cnt;
    }
    __syncthreads();
    int cnt = scnt;
    for (int k = tid; k < POST; k += 256) if (k >= cnt) ssel[k] = -1;
    __syncthreads();

    const int R1 = BATCH * POST * 7;
    const int R2 = R1 + BATCH * POST;
    for (int k = tid; k < POST; k += 256) {
        int j = ssel[k];
        float* ro = out + ((size_t)b * POST + k) * 7;
        float score = 0.0f, labelf = 1.0f;
        if (j >= 0) {
            u64 key = keys[j];
            int n = (int)(key & 0xffffffffULL);
            const float* bp = boxes + ((size_t)b * NBOX + n) * 7;
            #pragma unroll
            for (int c = 0; c < 7; ++c) ro[c] = bp[c];
            score = __uint_as_float(~(u32)(key >> 32));
            const float* cp = cls + ((size_t)b * NBOX + n) * 3;
            float c0 = cp[0], c1 = cp[1], c2 = cp[2];
            int lab = 0; float best = c0;
            if (c1 > best) { best = c1; lab = 1; }
            if (c2 > best) { lab = 2; }
            labelf = (float)(lab + 1);
        } else {
            #pragma unroll
            for (int c = 0; c < 7; ++c) ro[c] = 0.0f;
        }
        out[R1 + b * POST + k] = score;
        out[R2 + b * POST + k] = labelf;
    }
}

// ---------------------------------------------------------------------------
// Fallback NMS (round-0, proven): one 1024-thread WG per batch, LDS-resident.
// Used only if ws_size can't hold the 32 MB suppression matrix.
// ---------------------------------------------------------------------------
__global__ __launch_bounds__(1024) void k_nms(const u64* __restrict__ topkeys,
                                              const float* __restrict__ boxes,
                                              const float* __restrict__ cls,
                                              float* __restrict__ out) {
    __shared__ float sx1[PRE], sy1[PRE], sx2[PRE], sy2[PRE], sarea[PRE];
    __shared__ int   sorig[PRE];
    __shared__ u64   smask[PRE / 64];
    __shared__ int   ssel[POST];
    __shared__ int   scur;
    int b = blockIdx.x;
    int tid = threadIdx.x;
    const u64* keys = topkeys + (size_t)b * PRE;

    for (int i = tid; i < PRE; i += 1024) {
        u64 key = keys[i];
        int n = (int)(key & 0xffffffffULL);
        sorig[i] = n;
        const float* bp = boxes + ((size_t)b * NBOX + n) * 7;
        float cx = bp[0], cy = bp[1], dx = bp[3], dy = bp[4];
        float hx = __fmul_rn(dx, 0.5f), hy = __fmul_rn(dy, 0.5f);
        float x1 = __fsub_rn(cx, hx), x2 = __fadd_rn(cx, hx);
        float y1 = __fsub_rn(cy, hy), y2 = __fadd_rn(cy, hy);
        sx1[i] = x1; sx2[i] = x2; sy1[i] = y1; sy2[i] = y2;
        sarea[i] = __fmul_rn(__fsub_rn(x2, x1), __fsub_rn(y2, y1));
    }
    if (tid < PRE / 64) smask[tid] = ~0ULL;
    __syncthreads();

    int lane = tid & 63;
    int wv   = tid >> 6;
    for (int r = 0; r < POST; ++r) {
        if (tid < 64) {
            u64 w = smask[lane];
            u64 nz = __ballot(w != 0ULL);
            int j = -1;
            if (nz) {
                int fw = __ffsll(nz) - 1;
                u64 wf = shfl64(w, fw);
                j = (fw << 6) + __ffsll(wf) - 1;
            }
            if (lane == 0) { scur = j; ssel[r] = j; }
        }
        __syncthreads();
        int j = scur;
        if (j < 0) {
            for (int k = r + tid; k < POST; k += 1024) ssel[k] = -1;
            __syncthreads();
            break;
        }
        float x1j = sx1[j], x2j = sx2[j], y1j = sy1[j], y2j = sy2[j], aj = sarea[j];
        for (int wd = wv * 4; wd < wv * 4 + 4; ++wd) {
            u64 m = smask[wd];
            if (m == 0ULL) continue;
            int i = (wd << 6) + lane;
            float ix = fmaxf(__fsub_rn(fminf(sx2[i], x2j), fmaxf(sx1[i], x1j)), 0.0f);
            float iy = fmaxf(__fsub_rn(fminf(sy2[i], y2j), fmaxf(sy1[i], y1j)), 0.0f);
            float inter = __fmul_rn(ix, iy);
            float denom = __fadd_rn(__fsub_rn(__fadd_rn(sarea[i], aj), inter), 1e-8f);
            float iou = __fdiv_rn(inter, denom);
            u64 clr = __ballot(!(iou < 0.7f));
            if (lane == 0) smask[wd] = m & ~clr;
        }
        __syncthreads();
    }

    const int R1 = BATCH * POST * 7;
    const int R2 = R1 + BATCH * POST;
    for (int k = tid; k < POST; k += 1024) {
        int j = ssel[k];
        float* ro = out + ((size_t)b * POST + k) * 7;
        float score = 0.0f, labelf = 1.0f;
        if (j >= 0) {
            int n = sorig[j];
            const float* bp = boxes + ((size_t)b * NBOX + n) * 7;
            #pragma unroll
            for (int c = 0; c < 7; ++c) ro[c] = bp[c];
            u64 key = keys[j];
            score = __uint_as_float(~(u32)(key >> 32));
            const float* cp = cls + ((size_t)b * NBOX + n) * 3;
            float c0 = cp[0], c1 = cp[1], c2 = cp[2];
            int lab = 0; float best = c0;
            if (c1 > best) { best = c1; lab = 1; }
            if (c2 > best) { lab = 2; }
            labelf = (float)(lab + 1);
        } else {
            #pragma unroll
            for (int c = 0; c < 7; ++c) ro[c] = 0.0f;
        }
        out[R1 + b * POST + k] = score;
        out[R2 + b * POST + k] = labelf;
    }
}

extern "C" void kernel_launch(void* const* d_in, const int* in_sizes, int n_in,
                              void* d_out, int out_size, void* d_ws, size_t ws_size,
                              hipStream_t stream) {
    const float* boxes = (const float*)d_in[0]; // (B,N,7)
    const float* cls   = (const float*)d_in[1]; // (B,N,3)
    float* out = (float*)d_out;

    char* ws = (char*)d_ws;
    u64*   keysA = (u64*)(ws + 0);                       // 4 MB
    u64*   keysB = (u64*)(ws + 4194304);                 // 4 MB
    float* cx1   = (float*)(ws + 8388608);               // 5 x 256 KB coords
    float* cy1   = (float*)(ws + 8650752);
    float* cx2   = (float*)(ws + 8912896);
    float* cy2   = (float*)(ws + 9175040);
    float* car   = (float*)(ws + 9437184);
    u64*   flags = (u64*)(ws + 9699328);                 // 8 KB
    u64*   maskp = (u64*)(ws + 9707520);                 // 32 MB
    const size_t NEED = 9707520 + (size_t)BATCH * PRE * 64 * 8; // 43,261,952

    k_sortkeys4096<<<BATCH * 8, 1024, 0, stream>>>(cls, keysB);
    k_mergepath<<<BATCH * 4, 256, 0, stream>>>(keysB, keysA, 4);   // 8 -> 4
    k_mergepath<<<BATCH * 2, 256, 0, stream>>>(keysA, keysB, 2);   // 4 -> 2
    k_mergepath<<<BATCH, 256, 0, stream>>>(keysB, keysA, 1);       // 2 -> 1: topkeys

    if (ws_size >= NEED) {
        k_coords<<<(BATCH * PRE) / 256, 256, 0, stream>>>(keysA, boxes,
                                                          cx1, cy1, cx2, cy2, car, flags);
        k_iou<<<dim3(2080, BATCH), 256, 0, stream>>>(cx1, cy1, cx2, cy2, car,
                                                     maskp, flags);
        k_walk<<<BATCH, 256, 0, stream>>>(maskp, flags, keysA, boxes, cls, out);
    } else {
        k_nms<<<BATCH, 1024, 0, stream>>>(keysA, boxes, cls, out);
    }
}

// Round 6
// 310.625 us; speedup vs baseline: 1.0568x; 1.0568x over previous
//
#include <hip/hip_runtime.h>
#include <stdint.h>

#define BATCH 16
#define NBOX  32768
#define PRE   4096
#define POST  512

// LDS pad for u64 bitonic arrays: slot(i) = i + (i>>4).
#define PADIDX(i) ((i) + ((i) >> 4))

typedef unsigned long long u64;
typedef unsigned int u32;
typedef unsigned short u16;

__device__ inline u64 shfl64(u64 v, int src) {
    int lo = __shfl((int)(v & 0xffffffffULL), src);
    int hi = __shfl((int)(v >> 32), src);
    return ((u64)(u32)hi << 32) | (u32)lo;
}

// ---------------------------------------------------------------------------
// K1: fused keygen + LDS bitonic sort of a 4096-key chunk (ascending).
// key = (~score_bits)<<32 | box_index  -> ascending == lax.top_k order.
// ---------------------------------------------------------------------------
__global__ __launch_bounds__(1024) void k_sortkeys4096(const float* __restrict__ cls,
                                                       u64* __restrict__ out) {
    __shared__ u64 s[PRE + (PRE >> 4)];
    int g = blockIdx.x;                   // global chunk: g = b*8 + c
    u64* dst = out + (size_t)g * PRE;
    int tid = threadIdx.x;
    for (int i = tid; i < PRE; i += 1024) {
        int idx = g * PRE + i;            // global box index (b*NBOX + n)
        const float* c = cls + (size_t)idx * 3;
        float sc = fmaxf(fmaxf(c[0], c[1]), c[2]);
        u32 sb = __float_as_uint(sc);     // scores >= 0 -> monotonic bits
        s[PADIDX(i)] = ((u64)(~sb) << 32) | (u32)(idx & (NBOX - 1));
    }
    for (int k = 2; k <= PRE; k <<= 1) {
        for (int jj = k >> 1; jj > 0; jj >>= 1) {
            __syncthreads();
            for (int p = tid; p < PRE / 2; p += 1024) {
                int i = 2 * p - (p & (jj - 1));
                int l = i + jj;
                bool asc = ((i & k) == 0);
                u64 a = s[PADIDX(i)], b = s[PADIDX(l)];
                if ((a > b) == asc) { s[PADIDX(i)] = b; s[PADIDX(l)] = a; }
            }
        }
    }
    __syncthreads();
    for (int i = tid; i < PRE; i += 1024) dst[i] = s[PADIDX(i)];
}

// ---------------------------------------------------------------------------
// K2: merge-path merge of two ascending 4096-lists, keep smallest 4096.
// ---------------------------------------------------------------------------
__global__ __launch_bounds__(256) void k_mergepath(const u64* __restrict__ in,
                                                   u64* __restrict__ out, int npairs) {
    __shared__ u64 sA[PRE], sB[PRE];
    int b = blockIdx.x / npairs, p = blockIdx.x % npairs;
    const u64* A  = in + ((size_t)b * npairs * 2 + (size_t)p * 2) * PRE;
    const u64* Bp = A + PRE;
    u64* dst = out + ((size_t)b * npairs + p) * PRE;
    int tid = threadIdx.x;
    for (int i = tid; i < PRE; i += 256) { sA[i] = A[i]; sB[i] = Bp[i]; }
    __syncthreads();
    int d = tid * 16;
    int lo = d > PRE ? d - PRE : 0;
    int hi = d < PRE ? d : PRE;
    while (lo < hi) {
        int mid = (lo + hi) >> 1;
        if (sA[mid] < sB[d - 1 - mid]) lo = mid + 1; else hi = mid;
    }
    int a = lo, bi = d - lo;
    u64 av = a  < PRE ? sA[a]  : ~0ULL;
    u64 bv = bi < PRE ? sB[bi] : ~0ULL;
    u64 res[16];
    #pragma unroll
    for (int q = 0; q < 16; ++q) {
        bool ta = av < bv;
        res[q] = ta ? av : bv;
        if (ta) { ++a;  av = a  < PRE ? sA[a]  : ~0ULL; }
        else    { ++bi; bv = bi < PRE ? sB[bi] : ~0ULL; }
    }
    #pragma unroll
    for (int q = 0; q < 16; ++q) dst[d + q] = res[q];
}

// ---------------------------------------------------------------------------
// K3: per-candidate coord extraction (1 thread = 1 candidate).
// ---------------------------------------------------------------------------
__global__ __launch_bounds__(256) void k_coords(const u64* __restrict__ topkeys,
                                                const float* __restrict__ boxes,
                                                float* __restrict__ cx1,
                                                float* __restrict__ cy1,
                                                float* __restrict__ cx2,
                                                float* __restrict__ cy2,
                                                float* __restrict__ car) {
    int g = blockIdx.x * 256 + threadIdx.x;   // 0 .. B*PRE-1
    int b = g >> 12;                          // PRE = 4096
    u64 key = topkeys[g];
    int n = (int)(key & 0xffffffffULL);
    const float* bp = boxes + ((size_t)b * NBOX + n) * 7;
    float cx = bp[0], cy = bp[1], dx = bp[3], dy = bp[4];
    float hx = __fmul_rn(dx, 0.5f), hy = __fmul_rn(dy, 0.5f);
    float x1 = __fsub_rn(cx, hx), x2 = __fadd_rn(cx, hx);
    float y1 = __fsub_rn(cy, hy), y2 = __fadd_rn(cy, hy);
    cx1[g] = x1; cy1[g] = y1; cx2[g] = x2; cy2[g] = y2;
    car[g] = __fmul_rn(__fsub_rn(x2, x1), __fsub_rn(y2, y1));
}

// ---------------------------------------------------------------------------
// K4: pairwise suppression -> sparse per-row lists. Tile = (64-row blk, word).
// Row i (i = blk*64+r) collects {j > i : RN32(iou) >= 0.7} as u16 entries:
// lists[row] = 16B {slot0 unused->count, 7 entries}; >7 overflows to spill.
// Division-free exact threshold: RN32(p/q) >= 0.7f <=> p > (0.7f-2^-25)*q in f64.
// ---------------------------------------------------------------------------
__global__ __launch_bounds__(256) void k_iou(const float* __restrict__ cx1,
                                             const float* __restrict__ cy1,
                                             const float* __restrict__ cx2,
                                             const float* __restrict__ cy2,
                                             const float* __restrict__ car,
                                             u32* __restrict__ counts,
                                             u16* __restrict__ lists,
                                             u32* __restrict__ spcnt,
                                             u32* __restrict__ spill) {
    __shared__ float s1[64], s2[64], s3[64], s4[64], s5[64];
    int b = blockIdx.y;
    int t = blockIdx.x, blk = 0;
    while (t >= 64 - blk) { t -= 64 - blk; ++blk; }
    int wd = blk + t;
    size_t base = (size_t)b * PRE;
    int bb = b * PRE;
    int tid = threadIdx.x;
    if (tid < 64) {
        int i = blk * 64 + tid;
        s1[tid] = cx1[base + i]; s2[tid] = cy1[base + i];
        s3[tid] = cx2[base + i]; s4[tid] = cy2[base + i];
        s5[tid] = car[base + i];
    }
    __syncthreads();
    int w = tid >> 6, lane = tid & 63;
    int j = wd * 64 + lane;
    float jx1 = cx1[base + j], jy1 = cy1[base + j];
    float jx2 = cx2[base + j], jy2 = cy2[base + j];
    float ja  = car[base + j];
    const double M = (double)0.7f - 0x1p-25;   // exact rounding boundary
    int r0 = w * 16;
    #pragma unroll 4
    for (int r = 0; r < 16; ++r) {
        int i = blk * 64 + r0 + r;
        float rx1 = s1[r0 + r], ry1 = s2[r0 + r];
        float rx2 = s3[r0 + r], ry2 = s4[r0 + r], ra = s5[r0 + r];
        float ix = fmaxf(__fsub_rn(fminf(jx2, rx2), fmaxf(jx1, rx1)), 0.0f);
        float iy = fmaxf(__fsub_rn(fminf(jy2, ry2), fmaxf(jy1, ry1)), 0.0f);
        float inter = __fmul_rn(ix, iy);
        bool cand = (j > i) && (inter > 0.0f);
        u64 m = 0;
        if (__ballot(cand)) {
            float ssum = __fadd_rn(ja, ra);
            float d    = __fsub_rn(ssum, inter);
            float q    = __fadd_rn(d, 1e-8f);
            bool sup = cand && ((double)inter > M * (double)q);
            m = __ballot(sup);
        }
        if (lane == 0 && m) {
            u64 mm = m;
            while (mm) {
                int jj = __ffsll(mm) - 1; mm &= mm - 1;
                u32 slot = atomicAdd(&counts[bb + i], 1u);
                if (slot < 7)
                    lists[((size_t)(bb + i)) * 8 + 1 + slot] = (u16)(wd * 64 + jj);
                else {
                    u32 sp = atomicAdd(&spcnt[b], 1u);
                    if (sp < 4096) spill[(b << 12) + sp] = ((u32)i << 16) | (u32)(wd * 64 + jj);
                }
            }
        }
    }
}

// ---------------------------------------------------------------------------
// K5: greedy walk, all suppression state in LDS/registers. 1 wave walks;
// count==0 rows (common) cost ~30cy, list rows one broadcast ds_read_b128.
// ---------------------------------------------------------------------------
__global__ __launch_bounds__(256) void k_walk(const u32* __restrict__ counts,
                                              const u16* __restrict__ lists,
                                              const u32* __restrict__ spcnt,
                                              const u32* __restrict__ spill,
                                              const u64* __restrict__ topkeys,
                                              const float* __restrict__ boxes,
                                              const float* __restrict__ cls,
                                              float* __restrict__ out) {
    __shared__ uint4 lrow[PRE];        // 64 KB: (count,7 entries) per row
    __shared__ u32   lbits[128];       // has-suppression bitset (4096 bits)
    __shared__ u32   lspill[4096];     // 16 KB spill mirror
    __shared__ int   ssel[POST];
    __shared__ int   scnt, ssp;
    int b = blockIdx.x;
    int tid = threadIdx.x;
    const u64* keys = topkeys + (size_t)b * PRE;
    const uint4* listv = (const uint4*)(lists + ((size_t)b * PRE) * 8);

    if (tid < 128) lbits[tid] = 0;
    if (tid == 0) { u32 s = spcnt[b]; ssp = s > 4096u ? 4096 : (int)s; }
    __syncthreads();
    for (int i = tid; i < PRE; i += 256) {
        uint4 row = listv[i];
        u32 c = counts[b * PRE + i];
        row.x = (row.x & 0xFFFF0000u) | (c > 65535u ? 65535u : c);
        lrow[i] = row;
        if (c) atomicOr(&lbits[i >> 5], 1u << (i & 31));
    }
    __syncthreads();
    int spn = ssp;
    for (int q = tid; q < spn; q += 256) lspill[q] = spill[(b << 12) + q];
    __syncthreads();

    if (tid < 64) {
        int lane = tid;
        u64 act = ~0ULL;
        u64 hasl = ((u64)lbits[2 * lane + 1] << 32) | lbits[2 * lane];
        int cnt = 0;
        while (true) {
            u64 bal = __ballot(act != 0ULL);
            if (!bal) break;
            int fw = __ffsll(bal) - 1;
            u64 wsel = shfl64(act, fw);
            int i = (fw << 6) + __ffsll(wsel) - 1;
            if (lane == 0) ssel[cnt] = i;
            if (++cnt == POST) break;
            if (lane == fw) act &= ~(1ULL << (i & 63));
            u64 hb = shfl64(hasl, fw);
            if ((hb >> (i & 63)) & 1ULL) {
                uint4 row = lrow[i];               // uniform addr -> broadcast
                int c = (int)(row.x & 0xFFFFu);
                u64 m = 0;
                int e;
                e = (int)(row.x >> 16);      if (c > 0 && (e >> 6) == lane) m |= 1ULL << (e & 63);
                e = (int)(row.y & 0xFFFFu);  if (c > 1 && (e >> 6) == lane) m |= 1ULL << (e & 63);
                e = (int)(row.y >> 16);      if (c > 2 && (e >> 6) == lane) m |= 1ULL << (e & 63);
                e = (int)(row.z & 0xFFFFu);  if (c > 3 && (e >> 6) == lane) m |= 1ULL << (e & 63);
                e = (int)(row.z >> 16);      if (c > 4 && (e >> 6) == lane) m |= 1ULL << (e & 63);
                e = (int)(row.w & 0xFFFFu);  if (c > 5 && (e >> 6) == lane) m |= 1ULL << (e & 63);
                e = (int)(row.w >> 16);      if (c > 6 && (e >> 6) == lane) m |= 1ULL << (e & 63);
                if (c > 7) {                        // rare overflow: scan spill
                    for (int q = 0; q < spn; ++q) {
                        u32 en = lspill[q];
                        if ((int)(en >> 16) == i) {
                            int j2 = (int)(en & 0xFFFFu);
                            if ((j2 >> 6) == lane) m |= 1ULL << (j2 & 63);
                        }
                    }
                }
                act &= ~m;
            }
        }
        if (lane == 0) scnt = cnt;
    }
    __syncthreads();
    int cnt = scnt;
    for (int k = tid; k < POST; k += 256) if (k >= cnt) ssel[k] = -1;
    __syncthreads();

    const int R1 = BATCH * POST * 7;
    const int R2 = R1 + BATCH * POST;
    for (int k = tid; k < POST; k += 256) {
        int j = ssel[k];
        float* ro = out + ((size_t)b * POST + k) * 7;
        float score = 0.0f, labelf = 1.0f;
        if (j >= 0) {
            u64 key = keys[j];
            int n = (int)(key & 0xffffffffULL);
            const float* bp = boxes + ((size_t)b * NBOX + n) * 7;
            #pragma unroll
            for (int c = 0; c < 7; ++c) ro[c] = bp[c];
            score = __uint_as_float(~(u32)(key >> 32));
            const float* cp = cls + ((size_t)b * NBOX + n) * 3;
            float c0 = cp[0], c1 = cp[1], c2 = cp[2];
            int lab = 0; float best = c0;
            if (c1 > best) { best = c1; lab = 1; }
            if (c2 > best) { lab = 2; }
            labelf = (float)(lab + 1);
        } else {
            #pragma unroll
            for (int c = 0; c < 7; ++c) ro[c] = 0.0f;
        }
        out[R1 + b * POST + k] = score;
        out[R2 + b * POST + k] = labelf;
    }
}

// ---------------------------------------------------------------------------
// Fallback NMS (round-0, proven), used only if ws is too small.
// ---------------------------------------------------------------------------
__global__ __launch_bounds__(1024) void k_nms(const u64* __restrict__ topkeys,
                                              const float* __restrict__ boxes,
                                              const float* __restrict__ cls,
                                              float* __restrict__ out) {
    __shared__ float sx1[PRE], sy1[PRE], sx2[PRE], sy2[PRE], sarea[PRE];
    __shared__ int   sorig[PRE];
    __shared__ u64   smask[PRE / 64];
    __shared__ int   ssel[POST];
    __shared__ int   scur;
    int b = blockIdx.x;
    int tid = threadIdx.x;
    const u64* keys = topkeys + (size_t)b * PRE;

    for (int i = tid; i < PRE; i += 1024) {
        u64 key = keys[i];
        int n = (int)(key & 0xffffffffULL);
        sorig[i] = n;
        const float* bp = boxes + ((size_t)b * NBOX + n) * 7;
        float cx = bp[0], cy = bp[1], dx = bp[3], dy = bp[4];
        float hx = __fmul_rn(dx, 0.5f), hy = __fmul_rn(dy, 0.5f);
        float x1 = __fsub_rn(cx, hx), x2 = __fadd_rn(cx, hx);
        float y1 = __fsub_rn(cy, hy), y2 = __fadd_rn(cy, hy);
        sx1[i] = x1; sx2[i] = x2; sy1[i] = y1; sy2[i] = y2;
        sarea[i] = __fmul_rn(__fsub_rn(x2, x1), __fsub_rn(y2, y1));
    }
    if (tid < PRE / 64) smask[tid] = ~0ULL;
    __syncthreads();

    int lane = tid & 63;
    int wv   = tid >> 6;
    for (int r = 0; r < POST; ++r) {
        if (tid < 64) {
            u64 w = smask[lane];
            u64 nz = __ballot(w != 0ULL);
            int j = -1;
            if (nz) {
                int fw = __ffsll(nz) - 1;
                u64 wf = shfl64(w, fw);
                j = (fw << 6) + __ffsll(wf) - 1;
            }
            if (lane == 0) { scur = j; ssel[r] = j; }
        }
        __syncthreads();
        int j = scur;
        if (j < 0) {
            for (int k = r + tid; k < POST; k += 1024) ssel[k] = -1;
            __syncthreads();
            break;
        }
        float x1j = sx1[j], x2j = sx2[j], y1j = sy1[j], y2j = sy2[j], aj = sarea[j];
        for (int wd = wv * 4; wd < wv * 4 + 4; ++wd) {
            u64 m = smask[wd];
            if (m == 0ULL) continue;
            int i = (wd << 6) + lane;
            float ix = fmaxf(__fsub_rn(fminf(sx2[i], x2j), fmaxf(sx1[i], x1j)), 0.0f);
            float iy = fmaxf(__fsub_rn(fminf(sy2[i], y2j), fmaxf(sy1[i], y1j)), 0.0f);
            float inter = __fmul_rn(ix, iy);
            float denom = __fadd_rn(__fsub_rn(__fadd_rn(sarea[i], aj), inter), 1e-8f);
            float iou = __fdiv_rn(inter, denom);
            u64 clr = __ballot(!(iou < 0.7f));
            if (lane == 0) smask[wd] = m & ~clr;
        }
        __syncthreads();
    }

    const int R1 = BATCH * POST * 7;
    const int R2 = R1 + BATCH * POST;
    for (int k = tid; k < POST; k += 1024) {
        int j = ssel[k];
        float* ro = out + ((size_t)b * POST + k) * 7;
        float score = 0.0f, labelf = 1.0f;
        if (j >= 0) {
            int n = sorig[j];
            const float* bp = boxes + ((size_t)b * NBOX + n) * 7;
            #pragma unroll
            for (int c = 0; c < 7; ++c) ro[c] = bp[c];
            u64 key = keys[j];
            score = __uint_as_float(~(u32)(key >> 32));
            const float* cp = cls + ((size_t)b * NBOX + n) * 3;
            float c0 = cp[0], c1 = cp[1], c2 = cp[2];
            int lab = 0; float best = c0;
            if (c1 > best) { best = c1; lab = 1; }
            if (c2 > best) { lab = 2; }
            labelf = (float)(lab + 1);
        } else {
            #pragma unroll
            for (int c = 0; c < 7; ++c) ro[c] = 0.0f;
        }
        out[R1 + b * POST + k] = score;
        out[R2 + b * POST + k] = labelf;
    }
}

extern "C" void kernel_launch(void* const* d_in, const int* in_sizes, int n_in,
                              void* d_out, int out_size, void* d_ws, size_t ws_size,
                              hipStream_t stream) {
    const float* boxes = (const float*)d_in[0]; // (B,N,7)
    const float* cls   = (const float*)d_in[1]; // (B,N,3)
    float* out = (float*)d_out;

    char* ws = (char*)d_ws;
    u64*   keysA  = (u64*)(ws + 0);                  // 4 MB
    u64*   keysB  = (u64*)(ws + 4194304);            // 4 MB
    float* cx1    = (float*)(ws + 8388608);          // 5 x 256 KB coords
    float* cy1    = (float*)(ws + 8650752);
    float* cx2    = (float*)(ws + 8912896);
    float* cy2    = (float*)(ws + 9175040);
    float* car    = (float*)(ws + 9437184);
    u32*   counts = (u32*)(ws + 9699328);            // 256 KB (zeroed)
    u32*   spcnt  = (u32*)(ws + 9961472);            // 64 B   (zeroed)
    u32*   spill  = (u32*)(ws + 9961536);            // 256 KB
    u16*   lists  = (u16*)(ws + 10223680);           // 1 MB
    const size_t NEED = 10223680 + (size_t)BATCH * PRE * 8 * sizeof(u16); // 11,272,256

    k_sortkeys4096<<<BATCH * 8, 1024, 0, stream>>>(cls, keysB);
    k_mergepath<<<BATCH * 4, 256, 0, stream>>>(keysB, keysA, 4);   // 8 -> 4
    k_mergepath<<<BATCH * 2, 256, 0, stream>>>(keysA, keysB, 2);   // 4 -> 2
    k_mergepath<<<BATCH, 256, 0, stream>>>(keysB, keysA, 1);       // 2 -> 1: topkeys

    if (ws_size >= NEED) {
        hipMemsetAsync(ws + 9699328, 0, 262208, stream);   // counts + spcnt
        k_coords<<<(BATCH * PRE) / 256, 256, 0, stream>>>(keysA, boxes,
                                                          cx1, cy1, cx2, cy2, car);
        k_iou<<<dim3(2080, BATCH), 256, 0, stream>>>(cx1, cy1, cx2, cy2, car,
                                                     counts, lists, spcnt, spill);
        k_walk<<<BATCH, 256, 0, stream>>>(counts, lists, spcnt, spill,
                                          keysA, boxes, cls, out);
    } else {
        k_nms<<<BATCH, 1024, 0, stream>>>(keysA, boxes, cls, out);
    }
}

// Round 8
// 266.385 us; speedup vs baseline: 1.2323x; 1.1661x over previous
//
#include <hip/hip_runtime.h>
#include <stdint.h>

#define BATCH 16
#define NBOX  32768
#define PRE   4096
#define POST  512

// LDS pad for u64 bitonic arrays: slot(i) = i + (i>>4).
#define PADIDX(i) ((i) + ((i) >> 4))

typedef unsigned long long u64;
typedef unsigned int u32;
typedef unsigned short u16;

__device__ inline u64 shfl64(u64 v, int src) {
    int lo = __shfl((int)(v & 0xffffffffULL), src);
    int hi = __shfl((int)(v >> 32), src);
    return ((u64)(u32)hi << 32) | (u32)lo;
}

// ---------------------------------------------------------------------------
// K1: fused keygen + LDS bitonic sort of a 4096-key chunk (ascending).
// key = (~score_bits)<<32 | box_index  -> ascending == lax.top_k order.
// ---------------------------------------------------------------------------
__global__ __launch_bounds__(1024) void k_sortkeys4096(const float* __restrict__ cls,
                                                       u64* __restrict__ out) {
    __shared__ u64 s[PRE + (PRE >> 4)];
    int g = blockIdx.x;                   // global chunk: g = b*8 + c
    u64* dst = out + (size_t)g * PRE;
    int tid = threadIdx.x;
    for (int i = tid; i < PRE; i += 1024) {
        int idx = g * PRE + i;            // global box index (b*NBOX + n)
        const float* c = cls + (size_t)idx * 3;
        float sc = fmaxf(fmaxf(c[0], c[1]), c[2]);
        u32 sb = __float_as_uint(sc);     // scores >= 0 -> monotonic bits
        s[PADIDX(i)] = ((u64)(~sb) << 32) | (u32)(idx & (NBOX - 1));
    }
    for (int k = 2; k <= PRE; k <<= 1) {
        for (int jj = k >> 1; jj > 0; jj >>= 1) {
            __syncthreads();
            for (int p = tid; p < PRE / 2; p += 1024) {
                int i = 2 * p - (p & (jj - 1));
                int l = i + jj;
                bool asc = ((i & k) == 0);
                u64 a = s[PADIDX(i)], b = s[PADIDX(l)];
                if ((a > b) == asc) { s[PADIDX(i)] = b; s[PADIDX(l)] = a; }
            }
        }
    }
    __syncthreads();
    for (int i = tid; i < PRE; i += 1024) dst[i] = s[PADIDX(i)];
}

// ---------------------------------------------------------------------------
// K2: merge-path merge of two ascending 4096-lists, keep smallest 4096.
// ---------------------------------------------------------------------------
__global__ __launch_bounds__(256) void k_mergepath(const u64* __restrict__ in,
                                                   u64* __restrict__ out, int npairs) {
    __shared__ u64 sA[PRE], sB[PRE];
    int b = blockIdx.x / npairs, p = blockIdx.x % npairs;
    const u64* A  = in + ((size_t)b * npairs * 2 + (size_t)p * 2) * PRE;
    const u64* Bp = A + PRE;
    u64* dst = out + ((size_t)b * npairs + p) * PRE;
    int tid = threadIdx.x;
    for (int i = tid; i < PRE; i += 256) { sA[i] = A[i]; sB[i] = Bp[i]; }
    __syncthreads();
    int d = tid * 16;
    int lo = d > PRE ? d - PRE : 0;
    int hi = d < PRE ? d : PRE;
    while (lo < hi) {
        int mid = (lo + hi) >> 1;
        if (sA[mid] < sB[d - 1 - mid]) lo = mid + 1; else hi = mid;
    }
    int a = lo, bi = d - lo;
    u64 av = a  < PRE ? sA[a]  : ~0ULL;
    u64 bv = bi < PRE ? sB[bi] : ~0ULL;
    u64 res[16];
    #pragma unroll
    for (int q = 0; q < 16; ++q) {
        bool ta = av < bv;
        res[q] = ta ? av : bv;
        if (ta) { ++a;  av = a  < PRE ? sA[a]  : ~0ULL; }
        else    { ++bi; bv = bi < PRE ? sB[bi] : ~0ULL; }
    }
    #pragma unroll
    for (int q = 0; q < 16; ++q) dst[d + q] = res[q];
}

// ---------------------------------------------------------------------------
// K3: per-candidate coord extraction (1 thread = 1 candidate).
// ---------------------------------------------------------------------------
__global__ __launch_bounds__(256) void k_coords(const u64* __restrict__ topkeys,
                                                const float* __restrict__ boxes,
                                                float* __restrict__ cx1,
                                                float* __restrict__ cy1,
                                                float* __restrict__ cx2,
                                                float* __restrict__ cy2,
                                                float* __restrict__ car) {
    int g = blockIdx.x * 256 + threadIdx.x;   // 0 .. B*PRE-1
    int b = g >> 12;                          // PRE = 4096
    u64 key = topkeys[g];
    int n = (int)(key & 0xffffffffULL);
    const float* bp = boxes + ((size_t)b * NBOX + n) * 7;
    float cx = bp[0], cy = bp[1], dx = bp[3], dy = bp[4];
    float hx = __fmul_rn(dx, 0.5f), hy = __fmul_rn(dy, 0.5f);
    float x1 = __fsub_rn(cx, hx), x2 = __fadd_rn(cx, hx);
    float y1 = __fsub_rn(cy, hy), y2 = __fadd_rn(cy, hy);
    cx1[g] = x1; cy1[g] = y1; cx2[g] = x2; cy2[g] = y2;
    car[g] = __fmul_rn(__fsub_rn(x2, x1), __fsub_rn(y2, y1));
}

// ---------------------------------------------------------------------------
// K4: pairwise suppression -> sparse per-row lists. Tile = (64-row blk, word).
// Row i (i = blk*64+r) collects {j > i : RN32(iou) >= 0.7} as u16 entries:
// lists[row] = 16B {slot0 unused->count, 7 entries}; >7 overflows to spill.
// Division-free exact threshold: RN32(p/q) >= 0.7f <=> p > (0.7f-2^-25)*q in f64.
// ---------------------------------------------------------------------------
__global__ __launch_bounds__(256) void k_iou(const float* __restrict__ cx1,
                                             const float* __restrict__ cy1,
                                             const float* __restrict__ cx2,
                                             const float* __restrict__ cy2,
                                             const float* __restrict__ car,
                                             u32* __restrict__ counts,
                                             u16* __restrict__ lists,
                                             u32* __restrict__ spcnt,
                                             u32* __restrict__ spill) {
    __shared__ float s1[64], s2[64], s3[64], s4[64], s5[64];
    int b = blockIdx.y;
    int t = blockIdx.x, blk = 0;
    while (t >= 64 - blk) { t -= 64 - blk; ++blk; }
    int wd = blk + t;
    size_t base = (size_t)b * PRE;
    int bb = b * PRE;
    int tid = threadIdx.x;
    if (tid < 64) {
        int i = blk * 64 + tid;
        s1[tid] = cx1[base + i]; s2[tid] = cy1[base + i];
        s3[tid] = cx2[base + i]; s4[tid] = cy2[base + i];
        s5[tid] = car[base + i];
    }
    __syncthreads();
    int w = tid >> 6, lane = tid & 63;
    int j = wd * 64 + lane;
    float jx1 = cx1[base + j], jy1 = cy1[base + j];
    float jx2 = cx2[base + j], jy2 = cy2[base + j];
    float ja  = car[base + j];
    const double M = (double)0.7f - 0x1p-25;   // exact rounding boundary
    int r0 = w * 16;
    #pragma unroll 4
    for (int r = 0; r < 16; ++r) {
        int i = blk * 64 + r0 + r;
        float rx1 = s1[r0 + r], ry1 = s2[r0 + r];
        float rx2 = s3[r0 + r], ry2 = s4[r0 + r], ra = s5[r0 + r];
        float ix = fmaxf(__fsub_rn(fminf(jx2, rx2), fmaxf(jx1, rx1)), 0.0f);
        float iy = fmaxf(__fsub_rn(fminf(jy2, ry2), fmaxf(jy1, ry1)), 0.0f);
        float inter = __fmul_rn(ix, iy);
        bool cand = (j > i) && (inter > 0.0f);
        u64 m = 0;
        if (__ballot(cand)) {
            float ssum = __fadd_rn(ja, ra);
            float d    = __fsub_rn(ssum, inter);
            float q    = __fadd_rn(d, 1e-8f);
            bool sup = cand && ((double)inter > M * (double)q);
            m = __ballot(sup);
        }
        if (lane == 0 && m) {
            u64 mm = m;
            while (mm) {
                int jj = __ffsll(mm) - 1; mm &= mm - 1;
                u32 slot = atomicAdd(&counts[bb + i], 1u);
                if (slot < 7)
                    lists[((size_t)(bb + i)) * 8 + 1 + slot] = (u16)(wd * 64 + jj);
                else {
                    u32 sp = atomicAdd(&spcnt[b], 1u);
                    if (sp < 4096) spill[(b << 12) + sp] = ((u32)i << 16) | (u32)(wd * 64 + jj);
                }
            }
        }
    }
}

// ---------------------------------------------------------------------------
// K5: single-thread word-sequential greedy walk. Active mask = 64 u64 words
// in LDS; entries always have j>i so future-word clears are fire-and-forget
// ds atomicAnd (no read dependency). Per selection: ~10 VALU (no-list rows),
// one broadcast ds_read_b128 (list rows). No cross-lane ops at all.
// ---------------------------------------------------------------------------
__global__ __launch_bounds__(256) void k_walk(const u32* __restrict__ counts,
                                              const u16* __restrict__ lists,
                                              const u32* __restrict__ spcnt,
                                              const u32* __restrict__ spill,
                                              const u64* __restrict__ topkeys,
                                              const float* __restrict__ boxes,
                                              const float* __restrict__ cls,
                                              float* __restrict__ out) {
    __shared__ uint4 lrow[PRE];        // 64 KB: (count,7 entries) per row
    __shared__ u64   smask[64];        // active mask
    __shared__ u64   haslw[64];        // has-suppression-list bit per row
    __shared__ u32   lspill[4096];     // 16 KB spill mirror
    __shared__ int   ssel[POST];
    __shared__ int   scnt, ssp;
    int b = blockIdx.x;
    int tid = threadIdx.x;
    const u64* keys = topkeys + (size_t)b * PRE;
    const uint4* listv = (const uint4*)(lists + ((size_t)b * PRE) * 8);

    if (tid < 64) { smask[tid] = ~0ULL; haslw[tid] = 0ULL; }
    if (tid == 0) { u32 s = spcnt[b]; ssp = s > 4096u ? 4096 : (int)s; }
    __syncthreads();
    for (int i = tid; i < PRE; i += 256) {
        uint4 row = listv[i];
        u32 c = counts[b * PRE + i];
        row.x = (row.x & 0xFFFF0000u) | (c > 65535u ? 65535u : c);
        lrow[i] = row;
        if (c) atomicOr(&haslw[i >> 6], 1ULL << (i & 63));
    }
    __syncthreads();
    int spn = ssp;
    for (int q = tid; q < spn; q += 256) lspill[q] = spill[(b << 12) + q];
    __syncthreads();

    if (tid == 0) {
        int cnt = 0;
        for (int wd = 0; wd < 64 && cnt < POST; ++wd) {
            // same-wave DS ops are processed in order; guard anyway so the
            // atomicAnds from earlier words are complete before this read.
            asm volatile("s_waitcnt lgkmcnt(0)" ::: "memory");
            u64 w  = smask[wd];
            u64 hl = haslw[wd];
            while (w) {
                int t = __ffsll(w) - 1;
                w &= w - 1;
                int i = (wd << 6) + t;
                ssel[cnt++] = i;
                if (cnt == POST) break;
                if ((hl >> t) & 1ULL) {
                    uint4 row = lrow[i];           // one ds_read_b128
                    int c = (int)(row.x & 0xFFFFu);
                    int e;
                    #define APPLY(e) do { \
                        if ((e >> 6) == wd) w &= ~(1ULL << (e & 63)); \
                        else atomicAnd(&smask[e >> 6], ~(1ULL << (e & 63))); \
                    } while (0)
                    e = (int)(row.x >> 16);     if (c > 0) APPLY(e);
                    e = (int)(row.y & 0xFFFFu); if (c > 1) APPLY(e);
                    e = (int)(row.y >> 16);     if (c > 2) APPLY(e);
                    e = (int)(row.z & 0xFFFFu); if (c > 3) APPLY(e);
                    e = (int)(row.z >> 16);     if (c > 4) APPLY(e);
                    e = (int)(row.w & 0xFFFFu); if (c > 5) APPLY(e);
                    e = (int)(row.w >> 16);     if (c > 6) APPLY(e);
                    if (c > 7) {                   // rare overflow: scan spill
                        for (int q = 0; q < spn; ++q) {
                            u32 en = lspill[q];
                            if ((int)(en >> 16) == i) {
                                int e2 = (int)(en & 0xFFFFu);
                                APPLY(e2);
                            }
                        }
                    }
                    #undef APPLY
                }
            }
        }
        scnt = cnt;
    }
    __syncthreads();
    int cnt = scnt;
    for (int k = tid; k < POST; k += 256) if (k >= cnt) ssel[k] = -1;
    __syncthreads();

    const int R1 = BATCH * POST * 7;
    const int R2 = R1 + BATCH * POST;
    for (int k = tid; k < POST; k += 256) {
        int j = ssel[k];
        float* ro = out + ((size_t)b * POST + k) * 7;
        float score = 0.0f, labelf = 1.0f;
        if (j >= 0) {
            u64 key = keys[j];
            int n = (int)(key & 0xffffffffULL);
            const float* bp = boxes + ((size_t)b * NBOX + n) * 7;
            #pragma unroll
            for (int c = 0; c < 7; ++c) ro[c] = bp[c];
            score = __uint_as_float(~(u32)(key >> 32));
            const float* cp = cls + ((size_t)b * NBOX + n) * 3;
            float c0 = cp[0], c1 = cp[1], c2 = cp[2];
            int lab = 0; float best = c0;
            if (c1 > best) { best = c1; lab = 1; }
            if (c2 > best) { lab = 2; }
            labelf = (float)(lab + 1);
        } else {
            #pragma unroll
            for (int c = 0; c < 7; ++c) ro[c] = 0.0f;
        }
        out[R1 + b * POST + k] = score;
        out[R2 + b * POST + k] = labelf;
    }
}

// ---------------------------------------------------------------------------
// Fallback NMS (round-0, proven), used only if ws is too small.
// ---------------------------------------------------------------------------
__global__ __launch_bounds__(1024) void k_nms(const u64* __restrict__ topkeys,
                                              const float* __restrict__ boxes,
                                              const float* __restrict__ cls,
                                              float* __restrict__ out) {
    __shared__ float sx1[PRE], sy1[PRE], sx2[PRE], sy2[PRE], sarea[PRE];
    __shared__ int   sorig[PRE];
    __shared__ u64   smask[PRE / 64];
    __shared__ int   ssel[POST];
    __shared__ int   scur;
    int b = blockIdx.x;
    int tid = threadIdx.x;
    const u64* keys = topkeys + (size_t)b * PRE;

    for (int i = tid; i < PRE; i += 1024) {
        u64 key = keys[i];
        int n = (int)(key & 0xffffffffULL);
        sorig[i] = n;
        const float* bp = boxes + ((size_t)b * NBOX + n) * 7;
        float cx = bp[0], cy = bp[1], dx = bp[3], dy = bp[4];
        float hx = __fmul_rn(dx, 0.5f), hy = __fmul_rn(dy, 0.5f);
        float x1 = __fsub_rn(cx, hx), x2 = __fadd_rn(cx, hx);
        float y1 = __fsub_rn(cy, hy), y2 = __fadd_rn(cy, hy);
        sx1[i] = x1; sx2[i] = x2; sy1[i] = y1; sy2[i] = y2;
        sarea[i] = __fmul_rn(__fsub_rn(x2, x1), __fsub_rn(y2, y1));
    }
    if (tid < PRE / 64) smask[tid] = ~0ULL;
    __syncthreads();

    int lane = tid & 63;
    int wv   = tid >> 6;
    for (int r = 0; r < POST; ++r) {
        if (tid < 64) {
            u64 w = smask[lane];
            u64 nz = __ballot(w != 0ULL);
            int j = -1;
            if (nz) {
                int fw = __ffsll(nz) - 1;
                u64 wf = shfl64(w, fw);
                j = (fw << 6) + __ffsll(wf) - 1;
            }
            if (lane == 0) { scur = j; ssel[r] = j; }
        }
        __syncthreads();
        int j = scur;
        if (j < 0) {
            for (int k = r + tid; k < POST; k += 1024) ssel[k] = -1;
            __syncthreads();
            break;
        }
        float x1j = sx1[j], x2j = sx2[j], y1j = sy1[j], y2j = sy2[j], aj = sarea[j];
        for (int wd = wv * 4; wd < wv * 4 + 4; ++wd) {
            u64 m = smask[wd];
            if (m == 0ULL) continue;
            int i = (wd << 6) + lane;
            float ix = fmaxf(__fsub_rn(fminf(sx2[i], x2j), fmaxf(sx1[i], x1j)), 0.0f);
            float iy = fmaxf(__fsub_rn(fminf(sy2[i], y2j), fmaxf(sy1[i], y1j)), 0.0f);
            float inter = __fmul_rn(ix, iy);
            float denom = __fadd_rn(__fsub_rn(__fadd_rn(sarea[i], aj), inter), 1e-8f);
            float iou = __fdiv_rn(inter, denom);
            u64 clr = __ballot(!(iou < 0.7f));
            if (lane == 0) smask[wd] = m & ~clr;
        }
        __syncthreads();
    }

    const int R1 = BATCH * POST * 7;
    const int R2 = R1 + BATCH * POST;
    for (int k = tid; k < POST; k += 1024) {
        int j = ssel[k];
        float* ro = out + ((size_t)b * POST + k) * 7;
        float score = 0.0f, labelf = 1.0f;
        if (j >= 0) {
            int n = sorig[j];
            const float* bp = boxes + ((size_t)b * NBOX + n) * 7;
            #pragma unroll
            for (int c = 0; c < 7; ++c) ro[c] = bp[c];
            u64 key = keys[j];
            score = __uint_as_float(~(u32)(key >> 32));
            const float* cp = cls + ((size_t)b * NBOX + n) * 3;
            float c0 = cp[0], c1 = cp[1], c2 = cp[2];
            int lab = 0; float best = c0;
            if (c1 > best) { best = c1; lab = 1; }
            if (c2 > best) { lab = 2; }
            labelf = (float)(lab + 1);
        } else {
            #pragma unroll
            for (int c = 0; c < 7; ++c) ro[c] = 0.0f;
        }
        out[R1 + b * POST + k] = score;
        out[R2 + b * POST + k] = labelf;
    }
}

extern "C" void kernel_launch(void* const* d_in, const int* in_sizes, int n_in,
                              void* d_out, int out_size, void* d_ws, size_t ws_size,
                              hipStream_t stream) {
    const float* boxes = (const float*)d_in[0]; // (B,N,7)
    const float* cls   = (const float*)d_in[1]; // (B,N,3)
    float* out = (float*)d_out;

    char* ws = (char*)d_ws;
    u64*   keysA  = (u64*)(ws + 0);                  // 4 MB
    u64*   keysB  = (u64*)(ws + 4194304);            // 4 MB
    float* cx1    = (float*)(ws + 8388608);          // 5 x 256 KB coords
    float* cy1    = (float*)(ws + 8650752);
    float* cx2    = (float*)(ws + 8912896);
    float* cy2    = (float*)(ws + 9175040);
    float* car    = (float*)(ws + 9437184);
    u32*   counts = (u32*)(ws + 9699328);            // 256 KB (zeroed)
    u32*   spcnt  = (u32*)(ws + 9961472);            // 64 B   (zeroed)
    u32*   spill  = (u32*)(ws + 9961536);            // 256 KB
    u16*   lists  = (u16*)(ws + 10223680);           // 1 MB
    const size_t NEED = 10223680 + (size_t)BATCH * PRE * 8 * sizeof(u16); // 11,272,256

    k_sortkeys4096<<<BATCH * 8, 1024, 0, stream>>>(cls, keysB);
    k_mergepath<<<BATCH * 4, 256, 0, stream>>>(keysB, keysA, 4);   // 8 -> 4
    k_mergepath<<<BATCH * 2, 256, 0, stream>>>(keysA, keysB, 2);   // 4 -> 2
    k_mergepath<<<BATCH, 256, 0, stream>>>(keysB, keysA, 1);       // 2 -> 1: topkeys

    if (ws_size >= NEED) {
        hipMemsetAsync(ws + 9699328, 0, 262208, stream);   // counts + spcnt
        k_coords<<<(BATCH * PRE) / 256, 256, 0, stream>>>(keysA, boxes,
                                                          cx1, cy1, cx2, cy2, car);
        k_iou<<<dim3(2080, BATCH), 256, 0, stream>>>(cx1, cy1, cx2, cy2, car,
                                                     counts, lists, spcnt, spill);
        k_walk<<<BATCH, 256, 0, stream>>>(counts, lists, spcnt, spill,
                                          keysA, boxes, cls, out);
    } else {
        k_nms<<<BATCH, 1024, 0, stream>>>(keysA, boxes, cls, out);
    }
}